// Round 6
// baseline (8947.807 us; speedup 1.0000x reference)
//
#include <hip/hip_runtime.h>
#include <hip/hip_fp16.h>

#define H 161
#define G4 644            // 4*H gates
#define BB 32             // batch
#define TT 1000           // time
#define M_TOT (BB*TT)     // 32000 rows
#define GP 164            // padded gate-plane stride (halves), 8B-aligned quads
#define PR4 (4*GP)        // 656 halves per (d,m) row of pre
#define KSTR 200          // h row stride in halves (400 B: 16B-aligned, 2-way banks)
#define NW 12             // waves in lstm_scan
#define HT 11             // active hid-tiles (11*16 = 176 >= 161)

typedef _Float16 f16x8 __attribute__((ext_vector_type(8)));
typedef float f32x4 __attribute__((ext_vector_type(4)));
typedef _Float16 h2_t __attribute__((ext_vector_type(2)));

__device__ __forceinline__ h2_t bc_h2(unsigned int u) {
    return __builtin_bit_cast(h2_t, u);
}

__device__ __forceinline__ float sigm_f(float x) {
    return 1.0f / (1.0f + __expf(-x));
}
__device__ __forceinline__ float tanh_f(float x) {
    return 1.0f - 2.0f / (__expf(2.0f * x) + 1.0f);
}

// Barrier draining only LDS (lgkmcnt), not vmcnt: hcat stores and the pre
// prefetch loads stay in flight across step boundaries.
__device__ __forceinline__ void bar_lds() {
    __builtin_amdgcn_sched_barrier(0);
    asm volatile("s_waitcnt lgkmcnt(0)" ::: "memory");
    __builtin_amdgcn_s_barrier();
    __builtin_amdgcn_sched_barrier(0);
}

// ---------------------------------------------------------------------------
// pre_gemm: pre[d][m][gtype*GP + hid] = sum_k A[m][k]*wih_d[gtype*H+hid][k]+b
// Gate-major planes padded to GP=164 halves so lstm_scan's per-lane quad
// (4 consecutive hid, hid%4==0) is an aligned 8-byte load.
// ---------------------------------------------------------------------------
__global__ __launch_bounds__(256) void pre_gemm(
    const float* __restrict__ A,
    const float* __restrict__ wf, const float* __restrict__ wb,
    const float* __restrict__ bif, const float* __restrict__ bhf,
    const float* __restrict__ bib, const float* __restrict__ bhb,
    __half* __restrict__ pre)            // [2][M_TOT][PR4]
{
    const int BM = 64, BN = 64, BK = 16;
    int m0 = blockIdx.x * BM;
    int n0 = blockIdx.y * BN;
    __shared__ float As[BK][BM + 1];
    __shared__ float Bs[BK][BN + 1];
    int tid = threadIdx.x;
    int tx = tid & 15, ty = tid >> 4;
    float acc[4][4] = {};

    for (int k0 = 0; k0 < H; k0 += BK) {
        #pragma unroll
        for (int l = 0; l < (BM * BK) / 256; ++l) {
            int e = tid + l * 256;
            int mm = e / BK, kk = e % BK;
            int k = k0 + kk;
            As[kk][mm] = (k < H) ? A[(size_t)(m0 + mm) * H + k] : 0.f;
        }
        #pragma unroll
        for (int l = 0; l < (BN * BK) / 256; ++l) {
            int e = tid + l * 256;
            int nn = e / BK, kk = e % BK;
            int n = n0 + nn, k = k0 + kk;
            float v = 0.f;
            if (k < H && n < 2 * G4)
                v = (n < G4) ? wf[(size_t)n * H + k] : wb[(size_t)(n - G4) * H + k];
            Bs[kk][nn] = v;
        }
        __syncthreads();
        #pragma unroll
        for (int kk = 0; kk < BK; ++kk) {
            float a4[4], b4[4];
            #pragma unroll
            for (int i = 0; i < 4; ++i) a4[i] = As[kk][ty + 16 * i];
            #pragma unroll
            for (int j = 0; j < 4; ++j) b4[j] = Bs[kk][tx + 16 * j];
            #pragma unroll
            for (int i = 0; i < 4; ++i)
                #pragma unroll
                for (int j = 0; j < 4; ++j) acc[i][j] += a4[i] * b4[j];
        }
        __syncthreads();
    }

    #pragma unroll
    for (int i = 0; i < 4; ++i) {
        int m = m0 + ty + 16 * i;
        #pragma unroll
        for (int j = 0; j < 4; ++j) {
            int n = n0 + tx + 16 * j;
            if (n < 2 * G4) {
                int d = (n >= G4) ? 1 : 0;
                int g = n - d * G4;                  // gate-major 0..643
                int gtype = g / H;
                int hid = g - gtype * H;
                float bias = d ? (bib[g] + bhb[g]) : (bif[g] + bhf[g]);
                pre[(size_t)(d * M_TOT + m) * PR4 + gtype * GP + hid] =
                    __float2half(acc[i][j] + bias);
            }
        }
    }
}

// ---------------------------------------------------------------------------
// lstm_scan v6 (MFMA): 4 blocks = (2 batch-halves x 2 dir), 768 thr = 12 waves.
// Per step, the whole gate matvec for 16 batches is ONE GEMM:
//   [644 gates x 192 k] . [192 k x 16 batch]  via mfma_f32_16x16x32_f16.
// Wave w owns hid-tile w (16 hids): 4 gate-tiles x 6 k-tiles = 24 MFMA/step.
// A-frags (weights, 96 regs) are MFMA operands -> AGPR-native, no VALU-read
// tax (the structural killer of rounds 1-5: VALU-read weight arrays always
// ended in AGPR-copy or scratch-spill at 80..256 VGPRs).
// h double-buffered in LDS [16 batch][KSTR]; per wave only 6 ds_read_b128 of
// B-frags per step. C layout (col=lane&15=batch, row=(lane>>4)*4+reg) makes
// i,f,g,o of 4 hids land in ONE lane -> lane-local c update, no exchange,
// ONE lgkm-only barrier per step. pre prefetched 2 steps deep.
// ---------------------------------------------------------------------------
__global__ __launch_bounds__(768, 3) void lstm_scan(
    const __half* __restrict__ pre,      // [2][M_TOT][PR4]
    const float* __restrict__ whh_f,
    const float* __restrict__ whh_b,
    float* __restrict__ hcat)            // [M_TOT][2*H]
{
    const int bgrp = blockIdx.x;         // 0,1: batches [0..15] / [16..31]
    const int d = blockIdx.y;            // 0,1
    const int tid = threadIdx.x;
    const int w = tid >> 6;              // wave 0..11
    const int l = tid & 63;
    const int bl = l & 15;               // batch within group / A row sub
    const int hg = l >> 4;               // 0..3 k-group / hid-group
    const float* whh = d ? whh_b : whh_f;
    const bool wact = (w < HT);

    __shared__ __align__(16) __half h_sh[2][16][KSTR];   // 12.8 KB

    // ---- A fragments: wave w, gate-tile g covers whh rows g*H + w*16+bl,
    //      k = kt*32 + hg*8 + j. Zero-padded; addresses clamped in-bounds.
    const int hid0 = w * 16 + bl;
    const bool rowok = wact && (hid0 < H);
    const int hid0c = (hid0 < H) ? hid0 : (H - 1);
    f16x8 af[4][6];
    #pragma unroll
    for (int g = 0; g < 4; ++g) {
        const float* row = whh + ((size_t)g * H + hid0c) * H;
        #pragma unroll
        for (int kt = 0; kt < 6; ++kt) {
            f16x8 v;
            #pragma unroll
            for (int j = 0; j < 8; ++j) {
                int k = kt * 32 + hg * 8 + j;
                int kc = (k < H) ? k : (H - 1);
                float x = row[kc];
                v[j] = (_Float16)((rowok && k < H) ? x : 0.f);
            }
            af[g][kt] = v;
        }
    }

    // zero both h buffers (incl. the k-pad region, which must stay 0)
    {
        unsigned int* hz = (unsigned int*)h_sh;
        for (int i = tid; i < (int)(sizeof(h_sh) / 4); i += 768) hz[i] = 0u;
    }

    float c[4] = {0.f, 0.f, 0.f, 0.f};
    const int gbat = bgrp * 16 + bl;     // global batch 0..31
    const int hb = w * 16 + hg * 4;      // this lane's first hid
    const __half* pb0 = pre + ((size_t)d * M_TOT + (size_t)gbat * TT) * PR4 + hb;

    struct PreQ { uint2 gi, gf, gg, go; };
    #define LDP(tt_) ({                                                      \
        int tc_ = ((tt_) < TT) ? (tt_) : (TT - 1);                           \
        int t_  = d ? (TT - 1 - tc_) : tc_;                                  \
        const __half* pp_ = pb0 + (size_t)t_ * PR4;                          \
        PreQ r_;                                                             \
        r_.gi = *(const uint2*)(pp_);                                        \
        r_.gf = *(const uint2*)(pp_ + GP);                                   \
        r_.gg = *(const uint2*)(pp_ + 2 * GP);                               \
        r_.go = *(const uint2*)(pp_ + 3 * GP);                               \
        r_; })

    PreQ pA = {}, pB = {};
    if (wact) { pA = LDP(0); pB = LDP(1); }
    __syncthreads();

    #define SCAN_STEP(TTT, PJ, RB) {                                         \
        if (wact) {                                                          \
            PreQ pc = PJ;                                                    \
            PJ = LDP((TTT) + 2);          /* 2-steps-ahead prefetch */       \
            f16x8 bfr[6];                                                    \
            _Pragma("unroll")                                                \
            for (int kt = 0; kt < 6; ++kt)                                   \
                bfr[kt] = *(const f16x8*)&h_sh[RB][bl][kt * 32 + hg * 8];    \
            f32x4 zz = {0.f, 0.f, 0.f, 0.f};                                 \
            f32x4 ci = zz, cf = zz, cg = zz, co = zz;                        \
            _Pragma("unroll")                                                \
            for (int kt = 0; kt < 6; ++kt) {                                 \
                ci = __builtin_amdgcn_mfma_f32_16x16x32_f16(                 \
                    af[0][kt], bfr[kt], ci, 0, 0, 0);                        \
                cf = __builtin_amdgcn_mfma_f32_16x16x32_f16(                 \
                    af[1][kt], bfr[kt], cf, 0, 0, 0);                        \
                cg = __builtin_amdgcn_mfma_f32_16x16x32_f16(                 \
                    af[2][kt], bfr[kt], cg, 0, 0, 0);                        \
                co = __builtin_amdgcn_mfma_f32_16x16x32_f16(                 \
                    af[3][kt], bfr[kt], co, 0, 0, 0);                        \
            }                                                                \
            float pi[4], pf[4], pg[4], po[4];                                \
            { h2_t u0 = bc_h2(pc.gi.x), u1 = bc_h2(pc.gi.y);                 \
              pi[0] = (float)u0[0]; pi[1] = (float)u0[1];                    \
              pi[2] = (float)u1[0]; pi[3] = (float)u1[1]; }                  \
            { h2_t u0 = bc_h2(pc.gf.x), u1 = bc_h2(pc.gf.y);                 \
              pf[0] = (float)u0[0]; pf[1] = (float)u0[1];                    \
              pf[2] = (float)u1[0]; pf[3] = (float)u1[1]; }                  \
            { h2_t u0 = bc_h2(pc.gg.x), u1 = bc_h2(pc.gg.y);                 \
              pg[0] = (float)u0[0]; pg[1] = (float)u0[1];                    \
              pg[2] = (float)u1[0]; pg[3] = (float)u1[1]; }                  \
            { h2_t u0 = bc_h2(pc.go.x), u1 = bc_h2(pc.go.y);                 \
              po[0] = (float)u0[0]; po[1] = (float)u0[1];                    \
              po[2] = (float)u1[0]; po[3] = (float)u1[1]; }                  \
            float hv[4];                                                     \
            _Pragma("unroll")                                                \
            for (int r = 0; r < 4; ++r) {                                    \
                float iv = sigm_f(ci[r] + pi[r]);                            \
                float fv = sigm_f(cf[r] + pf[r]);                            \
                float gv = tanh_f(cg[r] + pg[r]);                            \
                float ov = sigm_f(co[r] + po[r]);                            \
                c[r] = fv * c[r] + iv * gv;                                  \
                hv[r] = ov * tanh_f(c[r]);                                   \
            }                                                                \
            int t = d ? (TT - 1 - (TTT)) : (TTT);                            \
            size_t hrow = ((size_t)gbat * TT + t) * (2 * H) + (size_t)d * H; \
            if (w < 10) {                 /* all 4 hids valid */             \
                hcat[hrow + hb + 0] = hv[0];                                 \
                hcat[hrow + hb + 1] = hv[1];                                 \
                hcat[hrow + hb + 2] = hv[2];                                 \
                hcat[hrow + hb + 3] = hv[3];                                 \
                short4 s4;                                                   \
                s4.x = __half_as_short(__float2half(hv[0]));                 \
                s4.y = __half_as_short(__float2half(hv[1]));                 \
                s4.z = __half_as_short(__float2half(hv[2]));                 \
                s4.w = __half_as_short(__float2half(hv[3]));                 \
                *(short4*)&h_sh[(RB) ^ 1][bl][hb] = s4;                      \
            } else {                      /* w==10: hid 160..175 tail */     \
                _Pragma("unroll")                                            \
                for (int r = 0; r < 4; ++r) {                                \
                    if (hb + r < H) {                                        \
                        hcat[hrow + hb + r] = hv[r];                         \
                        h_sh[(RB) ^ 1][bl][hb + r] = __float2half(hv[r]);    \
                    }                                                        \
                }                                                            \
            }                                                                \
        }                                                                    \
        bar_lds();                                                           \
    }

    for (int base = 0; base < TT; base += 2) {
        SCAN_STEP(base,     pA, 0)
        SCAN_STEP(base + 1, pB, 1)
    }
    #undef SCAN_STEP
    #undef LDP
}

// ---------------------------------------------------------------------------
// lin_gemm: out[m][n] = relu?(sum_k hcat[m][k]*W[n][k] + bl[n]) + res[m][n]
// ---------------------------------------------------------------------------
__global__ __launch_bounds__(256) void lin_gemm(
    const float* __restrict__ A,     // [M_TOT][2H]
    const float* __restrict__ W,     // [H][2H]
    const float* __restrict__ bl,    // [H]
    const float* __restrict__ res,   // [M_TOT][H]
    float* __restrict__ out,         // [M_TOT][H]
    int relu)
{
    const int BM = 64, BN = 64, BK = 16;
    const int K = 2 * H;
    int m0 = blockIdx.x * BM;
    int n0 = blockIdx.y * BN;
    __shared__ float As[BK][BM + 1];
    __shared__ float Bs[BK][BN + 1];
    int tid = threadIdx.x;
    int tx = tid & 15, ty = tid >> 4;
    float acc[4][4] = {};

    for (int k0 = 0; k0 < K; k0 += BK) {
        #pragma unroll
        for (int l = 0; l < (BM * BK) / 256; ++l) {
            int e = tid + l * 256;
            int mm = e / BK, kk = e % BK;
            int k = k0 + kk;
            As[kk][mm] = (k < K) ? A[(size_t)(m0 + mm) * K + k] : 0.f;
        }
        #pragma unroll
        for (int l = 0; l < (BN * BK) / 256; ++l) {
            int e = tid + l * 256;
            int nn = e / BK, kk = e % BK;
            int n = n0 + nn, k = k0 + kk;
            Bs[kk][nn] = (k < K && n < H) ? W[(size_t)n * K + k] : 0.f;
        }
        __syncthreads();
        #pragma unroll
        for (int kk = 0; kk < BK; ++kk) {
            float a4[4], b4[4];
            #pragma unroll
            for (int i = 0; i < 4; ++i) a4[i] = As[kk][ty + 16 * i];
            #pragma unroll
            for (int j = 0; j < 4; ++j) b4[j] = Bs[kk][tx + 16 * j];
            #pragma unroll
            for (int i = 0; i < 4; ++i)
                #pragma unroll
                for (int j = 0; j < 4; ++j) acc[i][j] += a4[i] * b4[j];
        }
        __syncthreads();
    }

    #pragma unroll
    for (int i = 0; i < 4; ++i) {
        int m = m0 + ty + 16 * i;
        #pragma unroll
        for (int j = 0; j < 4; ++j) {
            int n = n0 + tx + 16 * j;
            if (n < H) {
                float v = acc[i][j] + bl[n];
                if (relu) v = fmaxf(v, 0.f);
                v += res[(size_t)m * H + n];
                out[(size_t)m * H + n] = v;
            }
        }
    }
}

extern "C" void kernel_launch(void* const* d_in, const int* in_sizes, int n_in,
                              void* d_out, int out_size, void* d_ws, size_t ws_size,
                              hipStream_t stream) {
    const float* x = (const float*)d_in[0];

    char* ws = (char*)d_ws;
    __half* pre = (__half*)ws;                       // 2*32000*656*2 B = 84 MB
    float* hcat = (float*)(ws + (size_t)2 * M_TOT * PR4 * sizeof(__half));
    float* bufB = hcat + (size_t)M_TOT * 2 * H;      // 20.6 MB
    // d_out doubles as the layer-1 output buffer (total ws use ~146 MB).

    const float* cur = x;
    float* outs[3] = {(float*)d_out, bufB, (float*)d_out};

    for (int l = 0; l < 3; ++l) {
        const float* const* p = (const float* const*)(d_in + 1 + 10 * l);
        // p: wih_f whh_f bih_f bhh_f wih_b whh_b bih_b bhh_b W bl
        dim3 g1(M_TOT / 64, 21);
        pre_gemm<<<g1, 256, 0, stream>>>(cur, p[0], p[4], p[2], p[3], p[6], p[7], pre);
        lstm_scan<<<dim3(2, 2), 768, 0, stream>>>(pre, p[1], p[5], hcat);
        dim3 g2(M_TOT / 64, 3);
        lin_gemm<<<g2, 256, 0, stream>>>(hcat, p[8], p[9], cur, outs[l], (l < 2) ? 1 : 0);
        cur = outs[l];
    }
}